// Round 1
// baseline (1436.430 us; speedup 1.0000x reference)
//
#include <hip/hip_runtime.h>
#include <hip/hip_bf16.h>
#include <math.h>

// FFTConvNet: out = relu(Re(ifft2( (fft2(x) per-freq complex-contract W) )) + bias)
// B=32, CIN=COUT=64, H=W=128.
// Pipeline:
//   k_fft_rows      : x fp32 -> row-FFT -> XF (bf16 complex, ws[0..128MiB))
//   k_fft_cols(-1)  : column FFT in-place on XF
//   k_cgemm         : per-frequency (32x64)@(64x64) complex contraction -> Y (ws[128MiB..256MiB))
//   k_fft_cols(+1)  : column IFFT in-place on Y (unscaled)
//   k_ifft_rows_out : row IFFT + 1/16384 scale + bias + relu -> out fp32

#define PI2 6.28318530717958647692f

__device__ __forceinline__ float2 cmulf(float2 a, float2 b) {
  return make_float2(a.x * b.x - a.y * b.y, a.x * b.y + a.y * b.x);
}
__device__ __forceinline__ unsigned int pack_bf(float re, float im) {
  __hip_bfloat162 h;
  h.x = __float2bfloat16(re);
  h.y = __float2bfloat16(im);
  return *(unsigned int*)&h;
}
__device__ __forceinline__ float2 unpack_bf(unsigned int v) {
  // bf16 -> f32 is exact: shift into the top 16 bits.
  return make_float2(__uint_as_float(v << 16), __uint_as_float(v & 0xFFFF0000u));
}
__device__ __forceinline__ int br7(int i) { return __brev((unsigned)i) >> 25; }

// ---------------- Pass 1a: forward row FFTs (real fp32 in, bf16 complex out) ----------------
__global__ __launch_bounds__(256) void k_fft_rows(const float* __restrict__ x,
                                                  unsigned int* __restrict__ xf) {
  __shared__ float2 tw[64];
  __shared__ float2 rows[4][128];
  const int t = threadIdx.x, lane = t & 63, lr = t >> 6;
  if (t < 64) {
    float s, c;
    sincosf(-PI2 * (float)t * (1.0f / 128.0f), &s, &c);
    tw[t] = make_float2(c, s);  // exp(-2*pi*i*t/128)
  }
  const int rowbase = (blockIdx.x * 4 + lr) << 7;
  const float a0 = x[rowbase + lane];
  const float a1 = x[rowbase + lane + 64];
  rows[lr][br7(lane)] = make_float2(a0, 0.f);
  rows[lr][br7(lane + 64)] = make_float2(a1, 0.f);
  __syncthreads();
#pragma unroll
  for (int s = 0; s < 7; s++) {
    const int half = 1 << s;
    const int p = lane & (half - 1);
    const int i0 = ((lane >> s) << (s + 1)) + p;
    const int i1 = i0 + half;
    const float2 w = tw[p << (6 - s)];
    const float2 u = rows[lr][i0];
    const float2 v = rows[lr][i1];
    const float2 wv = cmulf(w, v);
    rows[lr][i0] = make_float2(u.x + wv.x, u.y + wv.y);
    rows[lr][i1] = make_float2(u.x - wv.x, u.y - wv.y);
    __syncthreads();
  }
  xf[rowbase + lane] = pack_bf(rows[lr][lane].x, rows[lr][lane].y);
  xf[rowbase + lane + 64] = pack_bf(rows[lr][lane + 64].x, rows[lr][lane + 64].y);
}

// ---------------- Pass 1b / 3a: column FFT/IFFT, in-place, bf16 complex ----------------
// sign = -1: forward, +1: inverse (unscaled). One block = 32 columns of one image.
__global__ __launch_bounds__(256) void k_fft_cols(unsigned int* __restrict__ buf, float sign) {
  __shared__ float2 tw[64];
  __shared__ float2 tile[128][33];  // [h][w-local], padded stride to avoid bank conflicts
  const int t = threadIdx.x;
  if (t < 64) {
    float s, c;
    sincosf(sign * PI2 * (float)t * (1.0f / 128.0f), &s, &c);
    tw[t] = make_float2(c, s);
  }
  const int img = blockIdx.x >> 2;
  const int w0 = (blockIdx.x & 3) * 32;
  unsigned int* base = buf + img * 16384 + w0;
  const int j = t & 31, hh = t >> 5;  // hh in [0,8)
#pragma unroll
  for (int it = 0; it < 16; it++) {
    const int h = it * 8 + hh;
    tile[br7(h)][j] = unpack_bf(base[h * 128 + j]);  // coalesced read, bit-rev scatter in LDS
  }
  __syncthreads();
#pragma unroll
  for (int s = 0; s < 7; s++) {
    const int half = 1 << s;
#pragma unroll
    for (int kk = 0; kk < 8; kk++) {
      const int k = kk * 8 + hh;  // butterfly index 0..63, disjoint pairs within a stage
      const int p = k & (half - 1);
      const int i0 = ((k >> s) << (s + 1)) + p;
      const int i1 = i0 + half;
      const float2 w = tw[p << (6 - s)];
      const float2 u = tile[i0][j];
      const float2 v = tile[i1][j];
      const float2 wv = cmulf(w, v);
      tile[i0][j] = make_float2(u.x + wv.x, u.y + wv.y);
      tile[i1][j] = make_float2(u.x - wv.x, u.y - wv.y);
    }
    __syncthreads();
  }
#pragma unroll
  for (int it = 0; it < 16; it++) {
    const int h = it * 8 + hh;
    base[h * 128 + j] = pack_bf(tile[h][j].x, tile[h][j].y);
  }
}

// ---------------- Pass 2: per-frequency complex contraction ----------------
// Block: 16 freqs (lanes) x all 32 b x 16 o (o-split x4 in grid). Loop c in chunks of 16.
// W fp32 read coalesced (64B/(o,c) segment) exactly once from HBM; XF staged in LDS.
__global__ __launch_bounds__(256) void k_cgemm(const unsigned int* __restrict__ xf,
                                               const float* __restrict__ wr,
                                               const float* __restrict__ wi,
                                               unsigned int* __restrict__ y) {
  __shared__ unsigned int xs[16][32][17];  // [c-chunk][b][f], pad 17 -> 2-way (free) banks
  const int t = threadIdx.x;
  const int fc = blockIdx.x >> 2, oq = blockIdx.x & 3;
  const int f0 = fc * 16;
  const int fl = t & 15;
  const int b0 = ((t >> 4) & 3) * 8;
  const int o0 = oq * 16 + (t >> 6) * 4;
  float2 acc[8][4] = {};
  const int lf = t & 15, lb = t >> 4;  // loader mapping
  for (int c0 = 0; c0 < 64; c0 += 16) {
    __syncthreads();  // protect xs against previous-iteration readers
#pragma unroll
    for (int cc = 0; cc < 16; cc++) {
#pragma unroll
      for (int bh = 0; bh < 2; bh++) {
        const int b = bh * 16 + lb;
        xs[cc][b][lf] = xf[(b * 64 + (c0 + cc)) * 16384 + f0 + lf];
      }
    }
    __syncthreads();
    for (int cc = 0; cc < 16; cc++) {
      const int c = c0 + cc;
      float wr4[4], wi4[4];
#pragma unroll
      for (int jo = 0; jo < 4; jo++) {
        const int widx = ((o0 + jo) * 64 + c) * 16384 + f0 + fl;
        wr4[jo] = wr[widx];
        wi4[jo] = wi[widx];
      }
      float2 xv[8];
#pragma unroll
      for (int ib = 0; ib < 8; ib++) xv[ib] = unpack_bf(xs[cc][b0 + ib][fl]);
#pragma unroll
      for (int ib = 0; ib < 8; ib++) {
        const float2 a = xv[ib];
#pragma unroll
        for (int jo = 0; jo < 4; jo++) {
          acc[ib][jo].x = fmaf(a.x, wr4[jo], acc[ib][jo].x);
          acc[ib][jo].x = fmaf(-a.y, wi4[jo], acc[ib][jo].x);
          acc[ib][jo].y = fmaf(a.x, wi4[jo], acc[ib][jo].y);
          acc[ib][jo].y = fmaf(a.y, wr4[jo], acc[ib][jo].y);
        }
      }
    }
  }
#pragma unroll
  for (int ib = 0; ib < 8; ib++) {
#pragma unroll
    for (int jo = 0; jo < 4; jo++) {
      y[((b0 + ib) * 64 + (o0 + jo)) * 16384 + f0 + fl] = pack_bf(acc[ib][jo].x, acc[ib][jo].y);
    }
  }
}

// ---------------- Pass 3b: inverse row FFTs + scale + bias + relu ----------------
__global__ __launch_bounds__(256) void k_ifft_rows_out(const unsigned int* __restrict__ y,
                                                       const float* __restrict__ bias,
                                                       float* __restrict__ out) {
  __shared__ float2 tw[64];
  __shared__ float2 rows[4][128];
  const int t = threadIdx.x, lane = t & 63, lr = t >> 6;
  if (t < 64) {
    float s, c;
    sincosf(PI2 * (float)t * (1.0f / 128.0f), &s, &c);
    tw[t] = make_float2(c, s);  // inverse twiddles exp(+2*pi*i*t/128)
  }
  const int row = blockIdx.x * 4 + lr;  // (b*64+o)*128 + h
  const int base = row << 7;
  rows[lr][br7(lane)] = unpack_bf(y[base + lane]);
  rows[lr][br7(lane + 64)] = unpack_bf(y[base + lane + 64]);
  __syncthreads();
#pragma unroll
  for (int s = 0; s < 7; s++) {
    const int half = 1 << s;
    const int p = lane & (half - 1);
    const int i0 = ((lane >> s) << (s + 1)) + p;
    const int i1 = i0 + half;
    const float2 w = tw[p << (6 - s)];
    const float2 u = rows[lr][i0];
    const float2 v = rows[lr][i1];
    const float2 wv = cmulf(w, v);
    rows[lr][i0] = make_float2(u.x + wv.x, u.y + wv.y);
    rows[lr][i1] = make_float2(u.x - wv.x, u.y - wv.y);
    __syncthreads();
  }
  const int o = (row >> 7) & 63;
  const float bb = bias[o];
  const float sc = 1.0f / 16384.0f;  // ifft2 normalization
  const float r0 = fmaf(rows[lr][lane].x, sc, bb);
  const float r1 = fmaf(rows[lr][lane + 64].x, sc, bb);
  out[base + lane] = fmaxf(r0, 0.f);
  out[base + lane + 64] = fmaxf(r1, 0.f);
}

extern "C" void kernel_launch(void* const* d_in, const int* in_sizes, int n_in,
                              void* d_out, int out_size, void* d_ws, size_t ws_size,
                              hipStream_t stream) {
  const float* x = (const float*)d_in[0];
  const float* wr = (const float*)d_in[1];
  const float* wi = (const float*)d_in[2];
  const float* bias = (const float*)d_in[3];
  float* out = (float*)d_out;

  const size_t XF_BYTES = 134217728;  // 2048 images * 16384 * 4B (bf16 complex)
  if (ws_size < 2 * XF_BYTES) {
    // Workspace too small: emit zeros (distinguishable failure signature).
    hipMemsetAsync(d_out, 0, (size_t)out_size * sizeof(float), stream);
    return;
  }
  unsigned int* XF = (unsigned int*)d_ws;
  unsigned int* Y = (unsigned int*)((char*)d_ws + XF_BYTES);

  k_fft_rows<<<65536, 256, 0, stream>>>(x, XF);
  k_fft_cols<<<8192, 256, 0, stream>>>(XF, -1.0f);
  k_cgemm<<<4096, 256, 0, stream>>>(XF, wr, wi, Y);
  k_fft_cols<<<8192, 256, 0, stream>>>(Y, 1.0f);
  k_ifft_rows_out<<<65536, 256, 0, stream>>>(Y, bias, out);
}

// Round 2
// 1207.922 us; speedup vs baseline: 1.1892x; 1.1892x over previous
//
#include <hip/hip_runtime.h>
#include <hip/hip_bf16.h>
#include <math.h>

// FFTConvNet: out = relu(Re(ifft2( (fft2(x) per-freq complex-contract W) )) + bias)
// B=32, CIN=COUT=64, H=W=128.
// Pipeline:
//   k_fft_rows      : x fp32 -> row-FFT (wave-shuffle, no LDS) -> XF bf16 complex
//   k_fft_cols(-1)  : column FFT in-place on XF (LDS tile)
//   k_cgemm         : per-freq complex contraction, global_load_lds + double-buffer
//   k_fft_cols(+1)  : column IFFT in-place on Y
//   k_ifft_rows_out : row IFFT (wave-shuffle) + 1/16384 + bias + relu -> out fp32

#define PI2 6.28318530717958647692f
typedef unsigned int uint32;

__device__ __forceinline__ float2 cmulf(float2 a, float2 b) {
  return make_float2(a.x * b.x - a.y * b.y, a.x * b.y + a.y * b.x);
}
__device__ __forceinline__ uint32 pack_bf(float re, float im) {
  __hip_bfloat162 h;
  h.x = __float2bfloat16(re);
  h.y = __float2bfloat16(im);
  return *(uint32*)&h;
}
__device__ __forceinline__ float2 unpack_bf(uint32 v) {
  return make_float2(__uint_as_float(v << 16), __uint_as_float(v & 0xFFFF0000u));
}
__device__ __forceinline__ int br7(int i) { return __brev((unsigned)i) >> 25; }

// ---------- In-wave 128-pt DIT FFT: lane l holds a = l and a = l+64 ----------
// Input must be loaded bit-reversed: e0 = in[br7(l)], e1 = in[br7(l)+1].
// Output is natural order: e0 -> bin l, e1 -> bin l+64. sign=-1 fwd, +1 inv.
template <int SGN>
__device__ __forceinline__ void wave_fft128(float2& e0, float2& e1, int l) {
#pragma unroll
  for (int s = 1; s <= 6; s++) {
    const int h = 1 << (s - 1);
    const int p = l & (h - 1);
    float sn, cs;
    __sincosf((float)SGN * PI2 * (float)p / (float)(2 * h), &sn, &cs);
    const float2 w = make_float2(cs, sn);
    const bool up = (l & h) != 0;
    const float2 o0 = make_float2(__shfl_xor(e0.x, h), __shfl_xor(e0.y, h));
    const float2 o1 = make_float2(__shfl_xor(e1.x, h), __shfl_xor(e1.y, h));
    const float2 u0 = up ? o0 : e0;
    const float2 m0 = up ? e0 : o0;
    const float2 u1 = up ? o1 : e1;
    const float2 m1 = up ? e1 : o1;
    const float2 t0 = cmulf(w, m0);
    const float2 t1 = cmulf(w, m1);
    e0 = up ? make_float2(u0.x - t0.x, u0.y - t0.y) : make_float2(u0.x + t0.x, u0.y + t0.y);
    e1 = up ? make_float2(u1.x - t1.x, u1.y - t1.y) : make_float2(u1.x + t1.x, u1.y + t1.y);
  }
  // stage 7: pair (l, l+64) in-register, twiddle W128^l
  float sn, cs;
  __sincosf((float)SGN * PI2 * (float)l * (1.0f / 128.0f), &sn, &cs);
  const float2 w = make_float2(cs, sn);
  const float2 t = cmulf(w, e1);
  const float2 u = e0;
  e0 = make_float2(u.x + t.x, u.y + t.y);
  e1 = make_float2(u.x - t.x, u.y - t.y);
}

// ---------------- Pass 1a: forward row FFTs (fp32 real in, bf16 complex out) ----------------
__global__ __launch_bounds__(256) void k_fft_rows(const float* __restrict__ x,
                                                  uint32* __restrict__ xf) {
  const int t = threadIdx.x, l = t & 63, wv = t >> 6;
  const int row = blockIdx.x * 4 + wv;
  const float* rp = x + (size_t)row * 128;
  const int brl = br7(l);  // even; br7(l+64) = brl+1
  const float2 v = *(const float2*)(rp + brl);
  float2 e0 = make_float2(v.x, 0.f);
  float2 e1 = make_float2(v.y, 0.f);
  wave_fft128<-1>(e0, e1, l);
  uint32* op = xf + (size_t)row * 128;
  op[l] = pack_bf(e0.x, e0.y);
  op[l + 64] = pack_bf(e1.x, e1.y);
}

// ---------------- Pass 1b / 3a: column FFT/IFFT, in-place, bf16 complex ----------------
__global__ __launch_bounds__(256) void k_fft_cols(uint32* __restrict__ buf, float sign) {
  __shared__ float2 tw[64];
  __shared__ float2 tile[128][33];
  const int t = threadIdx.x;
  if (t < 64) {
    float s, c;
    sincosf(sign * PI2 * (float)t * (1.0f / 128.0f), &s, &c);
    tw[t] = make_float2(c, s);
  }
  const int img = blockIdx.x >> 2;
  const int w0 = (blockIdx.x & 3) * 32;
  uint32* base = buf + img * 16384 + w0;
  const int j = t & 31, hh = t >> 5;
#pragma unroll
  for (int it = 0; it < 16; it++) {
    const int h = it * 8 + hh;
    tile[br7(h)][j] = unpack_bf(base[h * 128 + j]);
  }
  __syncthreads();
#pragma unroll
  for (int s = 0; s < 7; s++) {
    const int half = 1 << s;
#pragma unroll
    for (int kk = 0; kk < 8; kk++) {
      const int k = kk * 8 + hh;
      const int p = k & (half - 1);
      const int i0 = ((k >> s) << (s + 1)) + p;
      const int i1 = i0 + half;
      const float2 w = tw[p << (6 - s)];
      const float2 u = tile[i0][j];
      const float2 v = tile[i1][j];
      const float2 wv = cmulf(w, v);
      tile[i0][j] = make_float2(u.x + wv.x, u.y + wv.y);
      tile[i1][j] = make_float2(u.x - wv.x, u.y - wv.y);
    }
    __syncthreads();
  }
#pragma unroll
  for (int it = 0; it < 16; it++) {
    const int h = it * 8 + hh;
    base[h * 128 + j] = pack_bf(tile[h][j].x, tile[h][j].y);
  }
}

// ---------------- Pass 2: per-frequency complex contraction ----------------
// Block: 16 freqs x 16 o (o-quad in grid) x all 32 b. Lane map: fl=t&15 (freq),
// og=(t>>4)&3 (4 o's each), bw=t>>6 (8 b's each). W loads: 4 lines/instr, unique
// across the wave. XF: async global_load_lds dwordx4 into double-buffered LDS,
// staged one c-chunk (8) ahead; LDS reads are 4-lane broadcasts (conflict-free).
__global__ __launch_bounds__(256) void k_cgemm(const uint32* __restrict__ xf,
                                               const float* __restrict__ wr,
                                               const float* __restrict__ wi,
                                               uint32* __restrict__ y) {
  __shared__ uint32 xs[2][4096];  // [buf][(cc*32+b)*16 + f]
  const int t = threadIdx.x;
  const int fc = blockIdx.x >> 2, oq = blockIdx.x & 3;
  const int f0 = fc * 16;
  const int fl = t & 15;
  const int og = (t >> 4) & 3;
  const int bw = t >> 6;  // wave id
  const int o0 = oq * 16 + og * 4;
  const int b0 = bw * 8;
  const int l = t & 63;
  const int lr = l >> 2, fq = l & 3;  // staging: row-in-16, f-quad

  float2 acc[8][4] = {};

  auto stage = [&](int ci, int d) {
#pragma unroll
    for (int q = 0; q < 4; q++) {
      const int r = q * 64 + bw * 16 + lr;  // 0..255 = cc*32 + b
      const int cc = r >> 5, b = r & 31;
      const uint32* gp = xf + ((unsigned)(b * 64 + ci * 8 + cc) * 16384u +
                               (unsigned)(f0 + fq * 4));
      uint32* lp = &xs[d][(q * 64 + bw * 16) * 16];  // wave-uniform base
      __builtin_amdgcn_global_load_lds(
          (const __attribute__((address_space(1))) unsigned int*)gp,
          (__attribute__((address_space(3))) unsigned int*)lp, 16, 0, 0);
    }
  };

  stage(0, 0);
  for (int ci = 0; ci < 8; ci++) {
    __syncthreads();  // drains this chunk's async loads (vmcnt0 before barrier)
    if (ci < 7) stage(ci + 1, (ci + 1) & 1);  // prefetch next chunk, other buffer
    const int d = ci & 1;
    const int c0 = ci * 8;
#pragma unroll 2
    for (int cc = 0; cc < 8; cc++) {
      const int c = c0 + cc;
      const unsigned wbase = (unsigned)(o0 * 64 + c) * 16384u + (unsigned)(f0 + fl);
      float wr4[4], wi4[4];
#pragma unroll
      for (int jo = 0; jo < 4; jo++) {
        wr4[jo] = wr[wbase + (unsigned)jo * 1048576u];
        wi4[jo] = wi[wbase + (unsigned)jo * 1048576u];
      }
      float2 xv[8];
#pragma unroll
      for (int ib = 0; ib < 8; ib++)
        xv[ib] = unpack_bf(xs[d][(cc * 32 + b0 + ib) * 16 + fl]);
#pragma unroll
      for (int ib = 0; ib < 8; ib++) {
#pragma unroll
        for (int jo = 0; jo < 4; jo++) {
          acc[ib][jo].x = fmaf(xv[ib].x, wr4[jo], acc[ib][jo].x);
          acc[ib][jo].x = fmaf(-xv[ib].y, wi4[jo], acc[ib][jo].x);
          acc[ib][jo].y = fmaf(xv[ib].x, wi4[jo], acc[ib][jo].y);
          acc[ib][jo].y = fmaf(xv[ib].y, wr4[jo], acc[ib][jo].y);
        }
      }
    }
  }
#pragma unroll
  for (int ib = 0; ib < 8; ib++) {
#pragma unroll
    for (int jo = 0; jo < 4; jo++) {
      y[(unsigned)((b0 + ib) * 64 + o0 + jo) * 16384u + (unsigned)(f0 + fl)] =
          pack_bf(acc[ib][jo].x, acc[ib][jo].y);
    }
  }
}

// ---------------- Pass 3b: inverse row FFTs + scale + bias + relu ----------------
__global__ __launch_bounds__(256) void k_ifft_rows_out(const uint32* __restrict__ y,
                                                       const float* __restrict__ bias,
                                                       float* __restrict__ out) {
  const int t = threadIdx.x, l = t & 63, wv = t >> 6;
  const int row = blockIdx.x * 4 + wv;  // (b*64+o)*128 + h
  const uint32* rp = y + (size_t)row * 128;
  const int brl = br7(l);
  const uint2 u = *(const uint2*)(rp + brl);
  float2 e0 = unpack_bf(u.x);
  float2 e1 = unpack_bf(u.y);
  wave_fft128<1>(e0, e1, l);
  const int o = (row >> 7) & 63;
  const float bb = bias[o];
  const float sc = 1.0f / 16384.0f;
  float* op = out + (size_t)row * 128;
  op[l] = fmaxf(fmaf(e0.x, sc, bb), 0.f);
  op[l + 64] = fmaxf(fmaf(e1.x, sc, bb), 0.f);
}

extern "C" void kernel_launch(void* const* d_in, const int* in_sizes, int n_in,
                              void* d_out, int out_size, void* d_ws, size_t ws_size,
                              hipStream_t stream) {
  const float* x = (const float*)d_in[0];
  const float* wr = (const float*)d_in[1];
  const float* wi = (const float*)d_in[2];
  const float* bias = (const float*)d_in[3];
  float* out = (float*)d_out;

  const size_t XF_BYTES = 134217728;  // 2048 * 16384 * 4B (bf16 complex)
  if (ws_size < 2 * XF_BYTES) {
    hipMemsetAsync(d_out, 0, (size_t)out_size * sizeof(float), stream);
    return;
  }
  uint32* XF = (uint32*)d_ws;
  uint32* Y = (uint32*)((char*)d_ws + XF_BYTES);

  k_fft_rows<<<65536, 256, 0, stream>>>(x, XF);
  k_fft_cols<<<8192, 256, 0, stream>>>(XF, -1.0f);
  k_cgemm<<<4096, 256, 0, stream>>>(XF, wr, wi, Y);
  k_fft_cols<<<8192, 256, 0, stream>>>(Y, 1.0f);
  k_ifft_rows_out<<<65536, 256, 0, stream>>>(Y, bias, out);
}